// Round 5
// baseline (340.187 us; speedup 1.0000x reference)
//
#include <hip/hip_runtime.h>
#include <hip/hip_bf16.h>
#include <hip/hip_cooperative_groups.h>

namespace cg = cooperative_groups;

typedef short short8 __attribute__((ext_vector_type(8)));
typedef float f4 __attribute__((ext_vector_type(4)));

__device__ __forceinline__ short f2bfs(float f) {
    __hip_bfloat16 h = __float2bfloat16(f);
    return __builtin_bit_cast(short, h);
}

__device__ __forceinline__ unsigned packbf2(float a, float b, float s) {
    unsigned lo = (unsigned short)f2bfs(s * a);
    unsigned hi = (unsigned short)f2bfs(s * b);
    return (hi << 16) | lo;
}

#define MFMA(a, b, c) __builtin_amdgcn_mfma_f32_16x16x32_bf16(a, b, c, 0, 0, 0)

// ---------------------------------------------------------------------------
// gemmWT (cooperative, 320 blocks x 256 thr):
// Phase 1: blocks 0..255  -> 32x32 tile of WsT[n][d] = bf16(3w*(wv@wo)^T),
//          in-block split-K=4 (wave-per-512-k), LDS reduce, pre-scaled store.
//          blocks 256..319 -> shallow bias partials b2p[32][512] (64 MACs/thr,
//          bo folded into chunk r==0).
// grid.sync()
// Phase 2: blocks 0..255 -> 32x64 tile of t = hid @ WsT^T + 3w*bias.
//          B-frags are raw short8 (zero cvt); bias partials pre-loaded
//          before the MFMA loop, LDS-reduced after.
// ---------------------------------------------------------------------------
__global__ __launch_bounds__(256) void gemmWT(const float* __restrict__ wv,
                                              const float* __restrict__ wo,
                                              const float* __restrict__ bv,
                                              const float* __restrict__ bo,
                                              const float* __restrict__ w,
                                              const float* __restrict__ hid,
                                              short* __restrict__ WsT,
                                              float* __restrict__ b2p,
                                              float* __restrict__ t) {
    constexpr int K = 2048, N = 512, NT = 16;
    __shared__ float red[4][32][33];       // phase-1 reduce (16.9 KB)
    __shared__ float bred[4][64];          // phase-2 bias reduce

    const int tid = threadIdx.x;
    const int bx  = blockIdx.x;
    const int lane = tid & 63, wave = tid >> 6;
    const int ln = lane & 15, q = lane >> 4;

    // ---------------- Phase 1 ----------------
    if (bx >= 256) {                       // 64 bias-partial blocks
        const int g = (bx - 256) * 256 + tid;   // 0..16383
        const int o = g & 511;                  // output col
        const int r = g >> 9;                   // 0..31 (64-k chunk)
        float s = (r == 0) ? bo[o] : 0.f;
        const int j0 = r * 64;
#pragma unroll 8
        for (int j = j0; j < j0 + 64; ++j) s += bv[j] * wo[(size_t)j * N + o];
        b2p[r * 512 + o] = s;
    } else {
        const int row0 = (bx >> 4) * 32;   // d-tile
        const int col0 = (bx & 15) * 32;   // n-tile
        const int k0 = wave * 512;

        const float* pa0 = wv + (size_t)(row0 + ln) * K + k0 + q * 8;
        const float* pa1 = pa0 + (size_t)16 * K;
        const float* pb  = wo + (size_t)(k0 + q * 8) * N;

        float4 a00 = *(const float4*)pa0, a01 = *(const float4*)(pa0 + 4);
        float4 a10 = *(const float4*)pa1, a11 = *(const float4*)(pa1 + 4);
        float b0r[8], b1r[8];
#pragma unroll
        for (int j = 0; j < 8; ++j) {
            b0r[j] = pb[(size_t)j * N + col0 + ln];
            b1r[j] = pb[(size_t)j * N + col0 + 16 + ln];
        }

        f4 acc00 = {0,0,0,0}, acc01 = {0,0,0,0}, acc10 = {0,0,0,0}, acc11 = {0,0,0,0};

        for (int tt = 0; tt < NT; ++tt) {
            short8 af0, af1, bf0, bf1;
            af0[0]=f2bfs(a00.x); af0[1]=f2bfs(a00.y); af0[2]=f2bfs(a00.z); af0[3]=f2bfs(a00.w);
            af0[4]=f2bfs(a01.x); af0[5]=f2bfs(a01.y); af0[6]=f2bfs(a01.z); af0[7]=f2bfs(a01.w);
            af1[0]=f2bfs(a10.x); af1[1]=f2bfs(a10.y); af1[2]=f2bfs(a10.z); af1[3]=f2bfs(a10.w);
            af1[4]=f2bfs(a11.x); af1[5]=f2bfs(a11.y); af1[6]=f2bfs(a11.z); af1[7]=f2bfs(a11.w);
#pragma unroll
            for (int j = 0; j < 8; ++j) { bf0[j] = f2bfs(b0r[j]); bf1[j] = f2bfs(b1r[j]); }

            if (tt + 1 < NT) {             // prefetch next K-tile
                pa0 += 32; pa1 += 32; pb += (size_t)32 * N;
                a00 = *(const float4*)pa0; a01 = *(const float4*)(pa0 + 4);
                a10 = *(const float4*)pa1; a11 = *(const float4*)(pa1 + 4);
#pragma unroll
                for (int j = 0; j < 8; ++j) {
                    b0r[j] = pb[(size_t)j * N + col0 + ln];
                    b1r[j] = pb[(size_t)j * N + col0 + 16 + ln];
                }
            }
            acc00 = MFMA(af0, bf0, acc00); acc01 = MFMA(af0, bf1, acc01);
            acc10 = MFMA(af1, bf0, acc10); acc11 = MFMA(af1, bf1, acc11);
        }

#pragma unroll
        for (int r = 0; r < 4; ++r) {
            red[wave][q * 4 + r][ln]           = acc00[r];
            red[wave][q * 4 + r][ln + 16]      = acc01[r];
            red[wave][16 + q * 4 + r][ln]      = acc10[r];
            red[wave][16 + q * 4 + r][ln + 16] = acc11[r];
        }
        __syncthreads();

        const float wsc = 3.0f * w[0];
        const int n  = tid >> 3;           // 0..31 (local col)
        const int d0 = (tid & 7) * 4;      // 0..28 (local row, x4)
        float s0 = red[0][d0][n]     + red[1][d0][n]     + red[2][d0][n]     + red[3][d0][n];
        float s1 = red[0][d0 + 1][n] + red[1][d0 + 1][n] + red[2][d0 + 1][n] + red[3][d0 + 1][n];
        float s2 = red[0][d0 + 2][n] + red[1][d0 + 2][n] + red[2][d0 + 2][n] + red[3][d0 + 2][n];
        float s3 = red[0][d0 + 3][n] + red[1][d0 + 3][n] + red[2][d0 + 3][n] + red[3][d0 + 3][n];
        short* p = WsT + (size_t)(col0 + n) * 512 + row0 + d0;
        *(unsigned*)p       = packbf2(s0, s1, wsc);
        *(unsigned*)(p + 2) = packbf2(s2, s3, wsc);
    }

    __threadfence();
    cg::this_grid().sync();

    // ---------------- Phase 2 ----------------
    if (bx >= 256) return;

    constexpr int K2 = 512;
    const int col0 = (bx & 7) * 64;
    const int row0 = (bx >> 3) * 32;
    const int col = col0 + wave * 16 + ln;

    // bias partial pre-load (8 of 32 chunks for one of this block's 64 cols)
    const int cl = tid & 63, rr = tid >> 6;
    const float* bpp = b2p + (size_t)(rr * 8) * 512 + col0 + cl;
    float bp = 0.f;
#pragma unroll
    for (int k = 0; k < 8; ++k) bp += bpp[(size_t)k * 512];

    const float* pa0 = hid + (size_t)(row0 + ln) * K2 + q * 8;
    const float* pa1 = pa0 + (size_t)16 * K2;
    const short* pb  = WsT + (size_t)col * K2 + q * 8;

    float4 a00 = *(const float4*)pa0, a01 = *(const float4*)(pa0 + 4);
    float4 a10 = *(const float4*)pa1, a11 = *(const float4*)(pa1 + 4);
    short8 bf = *(const short8*)pb;

    f4 acc0 = {0,0,0,0}, acc1 = {0,0,0,0};

    for (int tt = 0; tt < NT; ++tt) {
        short8 af0, af1;
        af0[0]=f2bfs(a00.x); af0[1]=f2bfs(a00.y); af0[2]=f2bfs(a00.z); af0[3]=f2bfs(a00.w);
        af0[4]=f2bfs(a01.x); af0[5]=f2bfs(a01.y); af0[6]=f2bfs(a01.z); af0[7]=f2bfs(a01.w);
        af1[0]=f2bfs(a10.x); af1[1]=f2bfs(a10.y); af1[2]=f2bfs(a10.z); af1[3]=f2bfs(a10.w);
        af1[4]=f2bfs(a11.x); af1[5]=f2bfs(a11.y); af1[6]=f2bfs(a11.z); af1[7]=f2bfs(a11.w);
        short8 b = bf;
        if (tt + 1 < NT) {
            pa0 += 32; pa1 += 32; pb += 32;
            a00 = *(const float4*)pa0; a01 = *(const float4*)(pa0 + 4);
            a10 = *(const float4*)pa1; a11 = *(const float4*)(pa1 + 4);
            bf = *(const short8*)pb;
        }
        acc0 = MFMA(af0, b, acc0);
        acc1 = MFMA(af1, b, acc1);
    }

    __syncthreads();                       // red[] reuse barrier (phase 1 done)
    bred[rr][cl] = bp;
    __syncthreads();
    const int lc = wave * 16 + ln;
    const float wsc  = 3.0f * w[0];
    const float bias = wsc * (bred[0][lc] + bred[1][lc] + bred[2][lc] + bred[3][lc]);

#pragma unroll
    for (int r = 0; r < 4; ++r) {
        t[(size_t)(row0 + q * 4 + r) * N + col]      = acc0[r] + bias;
        t[(size_t)(row0 + 16 + q * 4 + r) * N + col] = acc1[r] + bias;
    }
}

// ---------------------------------------------------------------------------
// bcast: out[l,b,d] = mem[l,b,d] + t[b,d]   (t pre-scaled)
// Max-TLP: 25600 blocks x 256 thr, one float4 per thread. Nontemporal on the
// 210 MB mem/out stream so the 2 MB t stays L2-hot across its 50 re-reads.
// ---------------------------------------------------------------------------
__global__ __launch_bounds__(256) void bcast(const float* __restrict__ mem,
                                             const float* __restrict__ t,
                                             float* __restrict__ out) {
    const size_t idx = (size_t)blockIdx.x * 256 + threadIdx.x;  // float4 idx
    const int bd4 = (int)(idx & (131072 - 1));
    const f4 tv = ((const f4*)t)[bd4];
    const f4 m  = __builtin_nontemporal_load((const f4*)mem + idx);
    __builtin_nontemporal_store(m + tv, (f4*)out + idx);
}

extern "C" void kernel_launch(void* const* d_in, const int* in_sizes, int n_in,
                              void* d_out, int out_size, void* d_ws, size_t ws_size,
                              hipStream_t stream) {
    const float* momery = (const float*)d_in[0];   // [50,1024,512]
    const float* hid    = (const float*)d_in[1];   // [1024,512]
    const float* w      = (const float*)d_in[4];   // scalar
    const float* wv     = (const float*)d_in[13];  // [512,2048]
    const float* bv     = (const float*)d_in[14];  // [2048]
    const float* wo     = (const float*)d_in[15];  // [2048,512]
    const float* bo     = (const float*)d_in[16];  // [512]
    float* out = (float*)d_out;

    short* WsT = (short*)d_ws;                     // [512][512] bf16 (512 KB)
    float* b2p = (float*)(WsT + 262144);           // [32][512] fp32
    float* t   = b2p + 32 * 512;                   // [1024][512] fp32 (2 MB)

    // cooperative: phase1 (WsT + bias partials) -> grid.sync -> phase2 (t)
    void* args[] = {(void*)&wv, (void*)&wo, (void*)&bv, (void*)&bo, (void*)&w,
                    (void*)&hid, (void*)&WsT, (void*)&b2p, (void*)&t};
    hipLaunchCooperativeKernel((const void*)gemmWT, dim3(320), dim3(256),
                               args, 0, stream);

    // out = mem + t
    bcast<<<25600, 256, 0, stream>>>(momery, t, out);
}

// Round 6
// 234.670 us; speedup vs baseline: 1.4496x; 1.4496x over previous
//
#include <hip/hip_runtime.h>
#include <hip/hip_bf16.h>

typedef short short8 __attribute__((ext_vector_type(8)));
typedef float f4 __attribute__((ext_vector_type(4)));

__device__ __forceinline__ short f2bfs(float f) {
    __hip_bfloat16 h = __float2bfloat16(f);
    return __builtin_bit_cast(short, h);
}

__device__ __forceinline__ unsigned packbf2(float a, float b, float s) {
    unsigned lo = (unsigned short)f2bfs(s * a);
    unsigned hi = (unsigned short)f2bfs(s * b);
    return (hi << 16) | lo;
}

#define MFMA(a, b, c) __builtin_amdgcn_mfma_f32_16x16x32_bf16(a, b, c, 0, 0, 0)

// ---------------------------------------------------------------------------
// K1 gemmW: WsT[n][d] = bf16( 3w * (wv @ wo)[d][n] ),  fully reduced K=2048.
// Blocks 0..255: one 32x32 tile, 4 waves = in-block split-K=4, LDS reduce,
// transposed pre-scaled bf16 store.
// Blocks 256..319: bias partials b2p[32][512] (shallow: 64 MACs/thread,
// bo folded into chunk r==0).
// ---------------------------------------------------------------------------
__global__ __launch_bounds__(256) void gemmW(const float* __restrict__ wv,
                                             const float* __restrict__ wo,
                                             const float* __restrict__ bv,
                                             const float* __restrict__ bo,
                                             const float* __restrict__ w,
                                             short* __restrict__ WsT,
                                             float* __restrict__ b2p) {
    constexpr int K = 2048, N = 512, NT = 16;
    const int tid = threadIdx.x;
    const int bx  = blockIdx.x;

    if (bx >= 256) {                       // 64 bias-partial blocks
        const int g = (bx - 256) * 256 + tid;   // 0..16383
        const int o = g & 511;                  // output col
        const int r = g >> 9;                   // 0..31 (64-k chunk)
        float s = (r == 0) ? bo[o] : 0.f;
        const int j0 = r * 64;
#pragma unroll 8
        for (int j = j0; j < j0 + 64; ++j) s += bv[j] * wo[(size_t)j * N + o];
        b2p[r * 512 + o] = s;
        return;
    }

    __shared__ float red[4][32][33];       // 16.9 KB, padded

    const int row0 = (bx >> 4) * 32;       // d-tile
    const int col0 = (bx & 15) * 32;       // n-tile
    const int lane = tid & 63, wave = tid >> 6;
    const int ln = lane & 15, q = lane >> 4;
    const int k0 = wave * 512;

    const float* pa0 = wv + (size_t)(row0 + ln) * K + k0 + q * 8;
    const float* pa1 = pa0 + (size_t)16 * K;
    const float* pb  = wo + (size_t)(k0 + q * 8) * N;

    float4 a00 = *(const float4*)pa0, a01 = *(const float4*)(pa0 + 4);
    float4 a10 = *(const float4*)pa1, a11 = *(const float4*)(pa1 + 4);
    float b0r[8], b1r[8];
#pragma unroll
    for (int j = 0; j < 8; ++j) {
        b0r[j] = pb[(size_t)j * N + col0 + ln];
        b1r[j] = pb[(size_t)j * N + col0 + 16 + ln];
    }

    f4 acc00 = {0,0,0,0}, acc01 = {0,0,0,0}, acc10 = {0,0,0,0}, acc11 = {0,0,0,0};

    for (int t = 0; t < NT; ++t) {
        short8 af0, af1, bf0, bf1;
        af0[0]=f2bfs(a00.x); af0[1]=f2bfs(a00.y); af0[2]=f2bfs(a00.z); af0[3]=f2bfs(a00.w);
        af0[4]=f2bfs(a01.x); af0[5]=f2bfs(a01.y); af0[6]=f2bfs(a01.z); af0[7]=f2bfs(a01.w);
        af1[0]=f2bfs(a10.x); af1[1]=f2bfs(a10.y); af1[2]=f2bfs(a10.z); af1[3]=f2bfs(a10.w);
        af1[4]=f2bfs(a11.x); af1[5]=f2bfs(a11.y); af1[6]=f2bfs(a11.z); af1[7]=f2bfs(a11.w);
#pragma unroll
        for (int j = 0; j < 8; ++j) { bf0[j] = f2bfs(b0r[j]); bf1[j] = f2bfs(b1r[j]); }

        if (t + 1 < NT) {                  // prefetch next K-tile
            pa0 += 32; pa1 += 32; pb += (size_t)32 * N;
            a00 = *(const float4*)pa0; a01 = *(const float4*)(pa0 + 4);
            a10 = *(const float4*)pa1; a11 = *(const float4*)(pa1 + 4);
#pragma unroll
            for (int j = 0; j < 8; ++j) {
                b0r[j] = pb[(size_t)j * N + col0 + ln];
                b1r[j] = pb[(size_t)j * N + col0 + 16 + ln];
            }
        }
        acc00 = MFMA(af0, bf0, acc00); acc01 = MFMA(af0, bf1, acc01);
        acc10 = MFMA(af1, bf0, acc10); acc11 = MFMA(af1, bf1, acc11);
    }

    // stash this wave's 32x32 fp32 tile (D layout: row=q*4+r, col=ln)
#pragma unroll
    for (int r = 0; r < 4; ++r) {
        red[wave][q * 4 + r][ln]           = acc00[r];
        red[wave][q * 4 + r][ln + 16]      = acc01[r];
        red[wave][16 + q * 4 + r][ln]      = acc10[r];
        red[wave][16 + q * 4 + r][ln + 16] = acc11[r];
    }
    __syncthreads();

    // reduce 4 waves + scale + transposed bf16 store: 256 thr x 4 outputs
    const float wsc = 3.0f * w[0];
    const int n  = tid >> 3;               // 0..31 (local col)
    const int d0 = (tid & 7) * 4;          // 0..28 (local row, x4)
    float s0 = red[0][d0][n]     + red[1][d0][n]     + red[2][d0][n]     + red[3][d0][n];
    float s1 = red[0][d0 + 1][n] + red[1][d0 + 1][n] + red[2][d0 + 1][n] + red[3][d0 + 1][n];
    float s2 = red[0][d0 + 2][n] + red[1][d0 + 2][n] + red[2][d0 + 2][n] + red[3][d0 + 2][n];
    float s3 = red[0][d0 + 3][n] + red[1][d0 + 3][n] + red[2][d0 + 3][n] + red[3][d0 + 3][n];
    short* p = WsT + (size_t)(col0 + n) * 512 + row0 + d0;
    *(unsigned*)p       = packbf2(s0, s1, wsc);
    *(unsigned*)(p + 2) = packbf2(s2, s3, wsc);
}

// ---------------------------------------------------------------------------
// K2 gemmT: t[b][n] = hid[b][:] @ WsT[n][:] + 3w*(bv@wo + bo)[n]
// M=1024 N=512 K=512. 32x64 tiles -> grid (8,32) = 256 blocks, 4 waves
// (wave = 16-col quadrant). B-frags: raw short8 (zero cvt). Bias partials
// (8 per thread) are issued BEFORE the MFMA loop, LDS-reduced after.
// ---------------------------------------------------------------------------
__global__ __launch_bounds__(256) void gemmT(const float* __restrict__ hid,
                                             const short* __restrict__ WsT,
                                             const float* __restrict__ b2p,
                                             const float* __restrict__ w,
                                             float* __restrict__ t) {
    constexpr int K = 512, N = 512, NT = 16;
    __shared__ float bred[4][64];

    const int tid  = threadIdx.x;
    const int col0 = blockIdx.x * 64;
    const int row0 = blockIdx.y * 32;
    const int lane = tid & 63, wave = tid >> 6;
    const int ln = lane & 15, q = lane >> 4;
    const int col = col0 + wave * 16 + ln;

    // bias partial pre-load (8 of 32 chunks for one of this block's 64 cols)
    const int cl = tid & 63, rr = tid >> 6;
    const float* bpp = b2p + (size_t)(rr * 8) * 512 + col0 + cl;
    float bp = 0.f;
#pragma unroll
    for (int k = 0; k < 8; ++k) bp += bpp[(size_t)k * 512];

    const float* pa0 = hid + (size_t)(row0 + ln) * K + q * 8;
    const float* pa1 = pa0 + (size_t)16 * K;
    const short* pb  = WsT + (size_t)col * K + q * 8;

    float4 a00 = *(const float4*)pa0, a01 = *(const float4*)(pa0 + 4);
    float4 a10 = *(const float4*)pa1, a11 = *(const float4*)(pa1 + 4);
    short8 bf = *(const short8*)pb;

    f4 acc0 = {0,0,0,0}, acc1 = {0,0,0,0};

    for (int tt = 0; tt < NT; ++tt) {
        short8 af0, af1;
        af0[0]=f2bfs(a00.x); af0[1]=f2bfs(a00.y); af0[2]=f2bfs(a00.z); af0[3]=f2bfs(a00.w);
        af0[4]=f2bfs(a01.x); af0[5]=f2bfs(a01.y); af0[6]=f2bfs(a01.z); af0[7]=f2bfs(a01.w);
        af1[0]=f2bfs(a10.x); af1[1]=f2bfs(a10.y); af1[2]=f2bfs(a10.z); af1[3]=f2bfs(a10.w);
        af1[4]=f2bfs(a11.x); af1[5]=f2bfs(a11.y); af1[6]=f2bfs(a11.z); af1[7]=f2bfs(a11.w);
        short8 b = bf;
        if (tt + 1 < NT) {
            pa0 += 32; pa1 += 32; pb += 32;
            a00 = *(const float4*)pa0; a01 = *(const float4*)(pa0 + 4);
            a10 = *(const float4*)pa1; a11 = *(const float4*)(pa1 + 4);
            bf = *(const short8*)pb;
        }
        acc0 = MFMA(af0, b, acc0);
        acc1 = MFMA(af1, b, acc1);
    }

    bred[rr][cl] = bp;
    __syncthreads();
    const int lc = wave * 16 + ln;
    const float wsc  = 3.0f * w[0];
    const float bias = wsc * (bred[0][lc] + bred[1][lc] + bred[2][lc] + bred[3][lc]);

#pragma unroll
    for (int r = 0; r < 4; ++r) {
        t[(size_t)(row0 + q * 4 + r) * N + col]      = acc0[r] + bias;
        t[(size_t)(row0 + 16 + q * 4 + r) * N + col] = acc1[r] + bias;
    }
}

// ---------------------------------------------------------------------------
// K3 bcast: out[l,b,d] = mem[l,b,d] + t[b,d]   (t pre-scaled)
// Max-TLP: 25600 blocks x 256 thr, one float4 per thread. Nontemporal on the
// 210 MB mem/out stream so the 2 MB t stays L2-hot across its 50 re-reads.
// ---------------------------------------------------------------------------
__global__ __launch_bounds__(256) void bcast(const float* __restrict__ mem,
                                             const float* __restrict__ t,
                                             float* __restrict__ out) {
    const size_t idx = (size_t)blockIdx.x * 256 + threadIdx.x;  // float4 idx
    const int bd4 = (int)(idx & (131072 - 1));
    const f4 tv = ((const f4*)t)[bd4];
    const f4 m  = __builtin_nontemporal_load((const f4*)mem + idx);
    __builtin_nontemporal_store(m + tv, (f4*)out + idx);
}

extern "C" void kernel_launch(void* const* d_in, const int* in_sizes, int n_in,
                              void* d_out, int out_size, void* d_ws, size_t ws_size,
                              hipStream_t stream) {
    const float* momery = (const float*)d_in[0];   // [50,1024,512]
    const float* hid    = (const float*)d_in[1];   // [1024,512]
    const float* w      = (const float*)d_in[4];   // scalar
    const float* wv     = (const float*)d_in[13];  // [512,2048]
    const float* bv     = (const float*)d_in[14];  // [2048]
    const float* wo     = (const float*)d_in[15];  // [2048,512]
    const float* bo     = (const float*)d_in[16];  // [512]
    float* out = (float*)d_out;

    short* WsT = (short*)d_ws;                     // [512][512] bf16 (512 KB)
    float* b2p = (float*)(WsT + 262144);           // [32][512] fp32
    float* t   = b2p + 32 * 512;                   // [1024][512] fp32 (2 MB)

    // K1: WsT = bf16(3w * wv@wo)^T, b2p = shallow bias partials (+bo in r0)
    gemmW<<<320, 256, 0, stream>>>(wv, wo, bv, bo, w, WsT, b2p);
    // K2: t = hid @ WsT^T + scaled bias
    gemmT<<<dim3(8, 32), 256, 0, stream>>>(hid, WsT, b2p, w, t);
    // K3: out = mem + t
    bcast<<<25600, 256, 0, stream>>>(momery, t, out);
}